// Round 2
// baseline (3246.960 us; speedup 1.0000x reference)
//
#include <hip/hip_runtime.h>
#include <math.h>

#define EE 4
#define BB 16384
#define NN 1024
#define FF 64
#define HH 256
#define PED 63
#define TOPK 16
#define LINE 64
#define TS 32
#define NBX (BB/TS)   /* 512 */

/* workspace offsets (floats) */
#define OFF_KP   0u
#define OFF_VP   262144u
#define OFF_VPA  524288u
#define OFF_PE   786432u
#define OFF_PF   1818624u
#define OFF_EO   2867200u      /* 2*B*64 = 2097152 ; WP aliases its head (read before EO written) */
#define OFF_RW   4964352u
#define OFF_CNT  4997120u
#define OFF_LIST 4997128u
#define OFF_WP   OFF_EO

__device__ __forceinline__ float wred_sum(float v) {
#pragma unroll
    for (int off = 32; off > 0; off >>= 1) v += __shfl_xor(v, off, 64);
    return v;
}
__device__ __forceinline__ void wred_sum2(float& a, float& b) {
#pragma unroll
    for (int off = 32; off > 0; off >>= 1) {
        a += __shfl_xor(a, off, 64);
        b += __shfl_xor(b, off, 64);
    }
}

/* ------------ K0: wp[e] = wv[e] @ ad_w0[e][:64] ------------ */
__global__ __launch_bounds__(256) void k_prep(
    const float* __restrict__ wv, const float* __restrict__ aw0,
    float* __restrict__ wp)
{
    int e = blockIdx.x;
    __shared__ float sa[FF*FF];
    for (int i = threadIdx.x; i < FF*FF; i += 256)
        sa[i] = aw0[(size_t)e*128*FF + i];   /* top 64 rows */
    __syncthreads();
    int f = threadIdx.x & 63, dg = threadIdx.x >> 6;
    for (int d = dg; d < FF; d += 4) {
        const float* wr = wv + (size_t)e*FF*FF + d*FF;
        float a = 0.f;
        for (int c = 0; c < FF; ++c) a = fmaf(wr[c], sa[c*FF+f], a);
        wp[(size_t)e*FF*FF + d*FF + f] = a;
    }
}

/* ------------ K1: kp = mem_k@wk, vp = mem_v@wv, vpa = mem_v@wp ------------ */
__global__ __launch_bounds__(256) void k_proj(
    const float* __restrict__ mem_k, const float* __restrict__ mem_v,
    const float* __restrict__ wk, const float* __restrict__ wv,
    const float* __restrict__ wp,
    float* __restrict__ kp, float* __restrict__ vp, float* __restrict__ vpa)
{
    int e = blockIdx.x >> 6;          /* E*64 blocks, 16 rows each */
    int nbase = (blockIdx.x & 63) * 16;
    __shared__ float swk[FF*FF], swv[FF*FF], swp[FF*FF];
    for (int i = threadIdx.x; i < FF*FF; i += 256) {
        swk[i] = wk[(size_t)e*FF*FF + i];
        swv[i] = wv[(size_t)e*FF*FF + i];
        swp[i] = wp[(size_t)e*FF*FF + i];
    }
    __syncthreads();
    int r4 = threadIdx.x >> 6;
    int f  = threadIdx.x & 63;
#pragma unroll 1
    for (int it = 0; it < 4; ++it) {
        int n = nbase + it*4 + r4;
        const float* mk = mem_k + ((size_t)e*NN + n)*FF;
        const float* mv = mem_v + ((size_t)e*NN + n)*FF;
        float ak = 0.f, av = 0.f, aa = 0.f;
#pragma unroll 1
        for (int c4 = 0; c4 < 16; ++c4) {
            float4 k4 = *(const float4*)&mk[4*c4];
            float4 v4 = *(const float4*)&mv[4*c4];
#pragma unroll
            for (int kk = 0; kk < 4; ++kk) {
                float mkc = (kk==0)?k4.x:((kk==1)?k4.y:((kk==2)?k4.z:k4.w));
                float mvc = (kk==0)?v4.x:((kk==1)?v4.y:((kk==2)?v4.z:v4.w));
                int c = 4*c4 + kk;
                ak = fmaf(mkc, swk[c*FF+f], ak);
                av = fmaf(mvc, swv[c*FF+f], av);
                aa = fmaf(mvc, swp[c*FF+f], aa);
            }
        }
        kp [((size_t)e*NN+n)*FF + f] = ak;
        vp [((size_t)e*NN+n)*FF + f] = av;
        vpa[((size_t)e*NN+n)*FF + f] = aa;
    }
}

/* ------------ K2: routing + positional enc + param feats ------------ */
__global__ __launch_bounds__(256) void k_route(
    const float* __restrict__ x, const float* __restrict__ lines,
    const float* __restrict__ mg_w0, const float* __restrict__ mg_b0,
    const float* __restrict__ mg_w1, const float* __restrict__ mg_b1,
    float* __restrict__ pe_x, float* __restrict__ pfm,
    float* __restrict__ rawq, float* __restrict__ rw,
    int* __restrict__ counts, int* __restrict__ lists)
{
    __shared__ float slines[LINE*LINE];
    for (int i = threadIdx.x; i < LINE*LINE; i += 256) slines[i] = lines[i];
    __syncthreads();
    int b = blockIdx.x*256 + threadIdx.x;
    float4 xx = ((const float4*)x)[b];
    float c0 = xx.x, c1 = xx.y, c2 = xx.z, c3 = xx.w;

    float p = c3 * (float)(LINE-1);
    float pfl = floorf(p);
    float w = p - pfl;
    int il = (int)pfl;
    int ih = (int)fminf(fmaxf(pfl + 1.f, 0.f), (float)(LINE-1));
    for (int c = 0; c < FF; ++c) {
        float lo = slines[c*LINE+il], hi = slines[c*LINE+ih];
        pfm[(size_t)b*FF + c] = lo + w*(hi-lo);
    }
    float* pe = pe_x + (size_t)b*PED;
    pe[0]=c0; pe[1]=c1; pe[2]=c2;
    const float PI = 3.14159265358979323846f;
    float coords[3] = {c0,c1,c2};
#pragma unroll
    for (int cc = 0; cc < 3; ++cc) {
        float fr = PI;
        for (int k = 0; k < 10; ++k) {
            float s = coords[cc]*fr;
            pe[3 + cc*20 + k*2 + 0] = sinf(s);
            pe[3 + cc*20 + k*2 + 1] = cosf(s);
            fr *= 2.f;
        }
    }
    float acc[4] = {mg_b1[0], mg_b1[1], mg_b1[2], mg_b1[3]};
    for (int j = 0; j < 64; ++j) {
        float h = fmaf(c0, mg_w0[j], fmaf(c1, mg_w0[64+j], fmaf(c2, mg_w0[128+j], mg_b0[j])));
        h = fmaxf(h, 0.f);
#pragma unroll
        for (int e4 = 0; e4 < 4; ++e4) acc[e4] = fmaf(h, mg_w1[j*4+e4], acc[e4]);
    }
#pragma unroll
    for (int e4 = 0; e4 < 4; ++e4) rawq[(size_t)b*4 + e4] = acc[e4];
    float m = fmaxf(fmaxf(acc[0],acc[1]), fmaxf(acc[2],acc[3]));
    float ex[4], den = 0.f;
#pragma unroll
    for (int e4 = 0; e4 < 4; ++e4) { ex[e4] = expf(acc[e4]-m); den += ex[e4]; }
    float pr[4];
#pragma unroll
    for (int e4 = 0; e4 < 4; ++e4) pr[e4] = fmaxf(ex[e4]/den, 1e-8f);
    int i0 = 0;
#pragma unroll
    for (int e4 = 1; e4 < 4; ++e4) if (pr[e4] > pr[i0]) i0 = e4;
    int i1 = -1;
#pragma unroll
    for (int e4 = 0; e4 < 4; ++e4) {
        if (e4 == i0) continue;
        if (i1 < 0 || pr[e4] > pr[i1]) i1 = e4;
    }
    float vs = pr[i0] + pr[i1];
    rw[b*2+0] = pr[i0]/vs;
    rw[b*2+1] = pr[i1]/vs;
    int p0 = atomicAdd(&counts[i0], 1);
    lists[i0*BB + p0] = b*2 + 0;
    int p1 = atomicAdd(&counts[i1], 1);
    lists[i1*BB + p1] = b*2 + 1;
}

/* ------------ K3: expert pipeline — 8 waves x 4 samples, 2 barriers ------------ */
__global__ __launch_bounds__(512) void k_expert(
    const float* __restrict__ pe_x, const float* __restrict__ pfm,
    const float* __restrict__ kp, const float* __restrict__ vp,
    const float* __restrict__ vpa,
    const float* __restrict__ enc_w0, const float* __restrict__ enc_b0,
    const float* __restrict__ enc_wh, const float* __restrict__ enc_bh,
    const float* __restrict__ enc_wo, const float* __restrict__ enc_bo,
    const float* __restrict__ ln_g, const float* __restrict__ ln_b,
    const float* __restrict__ wq,
    const float* __restrict__ aw0, const float* __restrict__ ab0,
    const float* __restrict__ aw1, const float* __restrict__ ab1,
    const float* __restrict__ adg, const float* __restrict__ adb,
    const int* __restrict__ counts, const int* __restrict__ lists,
    float* __restrict__ eo)
{
    const int e = blockIdx.y;
    const int base = blockIdx.x * TS;
    const int cnt = counts[e];
    if (base >= cnt) return;

    __shared__ float sh[TS*HH];       /* 32KB: rows; later q in cols 64..127; pl = own rows */
    __shared__ float wr_l[8*TOPK];
    __shared__ int   tn_l[8*TOPK];
    __shared__ int   slist[TS];

    const int tid = threadIdx.x;
    const int lane = tid & 63;
    const int wv = tid >> 6;          /* 0..7 */
    const int r0 = wv*4;

    if (tid < TS) {
        int idx = base + tid;
        if (idx >= cnt) idx = cnt - 1;
        slist[tid] = lists[e*BB + idx];
    }
    __syncthreads();
    /* stage pe rows */
    for (int i = tid; i < TS*64; i += 512) {
        int s = i >> 6, j = i & 63;
        int bq = slist[s] >> 1;
        sh[s*HH + j] = (j < PED) ? pe_x[(size_t)bq*PED + j] : 0.f;
    }
    __syncthreads();
    /* ---- everything below is wave-private: no more barriers ---- */

    float acc[4][4];

    /* L0: 63 -> 256, lane owns cols 4*lane..+3 */
    {
        const float* W = enc_w0 + (size_t)e*PED*HH;
#pragma unroll
        for (int s = 0; s < 4; ++s)
#pragma unroll
            for (int j = 0; j < 4; ++j) acc[s][j] = 0.f;
#pragma unroll 1
        for (int k = 0; k < PED; ++k) {
            float4 w4 = *(const float4*)&W[k*HH + 4*lane];
#pragma unroll
            for (int s = 0; s < 4; ++s) {
                float hv = sh[(r0+s)*HH + k];
                acc[s][0] = fmaf(hv, w4.x, acc[s][0]);
                acc[s][1] = fmaf(hv, w4.y, acc[s][1]);
                acc[s][2] = fmaf(hv, w4.z, acc[s][2]);
                acc[s][3] = fmaf(hv, w4.w, acc[s][3]);
            }
        }
        float4 b4 = *(const float4*)&enc_b0[e*HH + 4*lane];
#pragma unroll
        for (int s = 0; s < 4; ++s) {
            float4 o;
            o.x = sinf(30.0f*(acc[s][0] + b4.x));
            o.y = sinf(30.0f*(acc[s][1] + b4.y));
            o.z = sinf(30.0f*(acc[s][2] + b4.z));
            o.w = sinf(30.0f*(acc[s][3] + b4.w));
            *(float4*)&sh[(r0+s)*HH + 4*lane] = o;
        }
    }

    /* L1, L2: 256 -> 256 */
#pragma unroll 1
    for (int layer = 0; layer < 2; ++layer) {
        const float* W = enc_wh + ((size_t)(e*2+layer))*HH*HH;
#pragma unroll
        for (int s = 0; s < 4; ++s)
#pragma unroll
            for (int j = 0; j < 4; ++j) acc[s][j] = 0.f;
#pragma unroll 1
        for (int k4 = 0; k4 < 64; ++k4) {
            float4 h4[4];
#pragma unroll
            for (int s = 0; s < 4; ++s)
                h4[s] = *(const float4*)&sh[(r0+s)*HH + 4*k4];
#pragma unroll
            for (int kk = 0; kk < 4; ++kk) {
                float4 w4 = *(const float4*)&W[(4*k4+kk)*HH + 4*lane];
#pragma unroll
                for (int s = 0; s < 4; ++s) {
                    float hv = (kk==0)?h4[s].x:((kk==1)?h4[s].y:((kk==2)?h4[s].z:h4[s].w));
                    acc[s][0] = fmaf(hv, w4.x, acc[s][0]);
                    acc[s][1] = fmaf(hv, w4.y, acc[s][1]);
                    acc[s][2] = fmaf(hv, w4.z, acc[s][2]);
                    acc[s][3] = fmaf(hv, w4.w, acc[s][3]);
                }
            }
        }
        float4 b4 = *(const float4*)&enc_bh[(e*2+layer)*HH + 4*lane];
#pragma unroll
        for (int s = 0; s < 4; ++s) {
            float4 o;
            o.x = sinf(30.0f*(acc[s][0] + b4.x));
            o.y = sinf(30.0f*(acc[s][1] + b4.y));
            o.z = sinf(30.0f*(acc[s][2] + b4.z));
            o.w = sinf(30.0f*(acc[s][3] + b4.w));
            *(float4*)&sh[(r0+s)*HH + 4*lane] = o;
        }
    }

    /* out layer: 256 -> 64, lane = out col; smlp in regs */
    float smlp_r[4];
    {
        const float* W = enc_wo + (size_t)e*HH*FF;
        float a2o[4] = {0.f,0.f,0.f,0.f};
#pragma unroll 1
        for (int k4 = 0; k4 < 64; ++k4) {
            float4 h4[4];
#pragma unroll
            for (int s = 0; s < 4; ++s)
                h4[s] = *(const float4*)&sh[(r0+s)*HH + 4*k4];
#pragma unroll
            for (int kk = 0; kk < 4; ++kk) {
                float w = W[(4*k4+kk)*FF + lane];
#pragma unroll
                for (int s = 0; s < 4; ++s) {
                    float hv = (kk==0)?h4[s].x:((kk==1)?h4[s].y:((kk==2)?h4[s].z:h4[s].w));
                    a2o[s] = fmaf(hv, w, a2o[s]);
                }
            }
        }
        float bv = enc_bo[e*FF + lane];
#pragma unroll
        for (int s = 0; s < 4; ++s) smlp_r[s] = a2o[s] + bv;
    }

    /* LN + q: lnv scratch in row cols 0..63, q stored in row cols 64..127 */
    {
        const float* Wq = wq + (size_t)e*FF*FF;
        float g = ln_g[lane], bb2 = ln_b[lane];
#pragma unroll 1
        for (int s = 0; s < 4; ++s) {
            float hv = smlp_r[s];
            float sm = hv, s2 = hv*hv;
            wred_sum2(sm, s2);
            float mean = sm * (1.f/64.f);
            float var = s2 * (1.f/64.f) - mean*mean;
            float lnv = (hv - mean) * rsqrtf(var + 1e-5f) * g + bb2;
            sh[(r0+s)*HH + lane] = lnv;
            float qa = 0.f;
#pragma unroll 1
            for (int c4 = 0; c4 < 16; ++c4) {
                float4 l4 = *(const float4*)&sh[(r0+s)*HH + 4*c4];
                qa = fmaf(l4.x, Wq[(4*c4+0)*FF + lane], qa);
                qa = fmaf(l4.y, Wq[(4*c4+1)*FF + lane], qa);
                qa = fmaf(l4.z, Wq[(4*c4+2)*FF + lane], qa);
                qa = fmaf(l4.w, Wq[(4*c4+3)*FF + lane], qa);
            }
            sh[(r0+s)*HH + 64 + lane] = qa;
        }
    }

    /* scores: lane owns key row c*64+lane, read kp direct from global (L2) */
    float sc[4][16];
    {
        const float* kpe = kp + (size_t)e*NN*FF;
#pragma unroll 1
        for (int c = 0; c < 16; ++c) {
            const float4* krow = (const float4*)(kpe + (size_t)(c*64+lane)*FF);
            float a0 = 0.f, a1 = 0.f, a2s = 0.f, a3 = 0.f;
#pragma unroll
            for (int f4 = 0; f4 < 16; ++f4) {
                float4 k4 = krow[f4];
                float4 q0 = *(const float4*)&sh[(r0+0)*HH + 64 + 4*f4];
                float4 q1 = *(const float4*)&sh[(r0+1)*HH + 64 + 4*f4];
                float4 q2 = *(const float4*)&sh[(r0+2)*HH + 64 + 4*f4];
                float4 q3 = *(const float4*)&sh[(r0+3)*HH + 64 + 4*f4];
                a0 = fmaf(k4.x,q0.x,fmaf(k4.y,q0.y,fmaf(k4.z,q0.z,fmaf(k4.w,q0.w,a0))));
                a1 = fmaf(k4.x,q1.x,fmaf(k4.y,q1.y,fmaf(k4.z,q1.z,fmaf(k4.w,q1.w,a1))));
                a2s= fmaf(k4.x,q2.x,fmaf(k4.y,q2.y,fmaf(k4.z,q2.z,fmaf(k4.w,q2.w,a2s))));
                a3 = fmaf(k4.x,q3.x,fmaf(k4.y,q3.y,fmaf(k4.z,q3.z,fmaf(k4.w,q3.w,a3))));
            }
            sc[0][c]=a0; sc[1][c]=a1; sc[2][c]=a2s; sc[3][c]=a3;
        }
    }

    /* top-16 + adapter, per sample; pl = wave's own rows (h/q dead) */
    const float* vpe  = vp  + (size_t)e*NN*FF;
    const float* vpae = vpa + (size_t)e*NN*FF;
    const float agv = adg[e*FF + lane], abv = adb[e*FF + lane];
    const float ab1v = ab1[e*FF + lane];
    const float* w1p = aw1 + (size_t)e*FF*FF;
    float* plw = &sh[r0*HH];          /* 1024 floats, wave-private */

#pragma unroll 1
    for (int u = 0; u < 4; ++u) {
        int s = r0 + u;
        int entry = slist[s];
        int bq = entry >> 1;
        float sc_cur[16];
#pragma unroll
        for (int c = 0; c < 16; ++c)
            sc_cur[c] = (u==0)?sc[0][c]:((u==1)?sc[1][c]:((u==2)?sc[2][c]:sc[3][c]));

        /* pf half of adapter layer 1 */
        float pp = ab0[e*FF + lane];
        {
            const float* a0b = aw0 + ((size_t)e*128 + 64)*FF;
            const float* pfr = pfm + (size_t)bq*FF;
#pragma unroll 1
            for (int c4 = 0; c4 < 16; ++c4) {
                float4 p4 = *(const float4*)&pfr[4*c4];
                pp = fmaf(p4.x, a0b[(4*c4+0)*FF + lane], pp);
                pp = fmaf(p4.y, a0b[(4*c4+1)*FF + lane], pp);
                pp = fmaf(p4.z, a0b[(4*c4+2)*FF + lane], pp);
                pp = fmaf(p4.w, a0b[(4*c4+3)*FF + lane], pp);
            }
        }

        unsigned taken = 0u;
        bool need = true;
        float bv = -1e30f; int bn = 0x7fffffff;
        float v0max = 0.f, wsum = 0.f;
        float parr[16];
#pragma unroll
        for (int r = 0; r < TOPK; ++r) {
            if (need) {
                bv = -1e30f; bn = 0x7fffffff;
#pragma unroll
                for (int c = 0; c < 16; ++c) {
                    float v = sc_cur[c];
                    int n = c*64 + lane;
                    bool ok = !((taken >> c) & 1u);
                    bool better = ok && (v > bv || (v == bv && n < bn));
                    bv = better ? v : bv;
                    bn = better ? n : bn;
                }
                need = false;
            }
            float rv = bv; int rn = bn;
#pragma unroll
            for (int off = 32; off > 0; off >>= 1) {
                float ov = __shfl_xor(rv, off, 64);
                int on = __shfl_xor(rn, off, 64);
                bool better = (ov > rv) || (ov == rv && on < rn);
                rv = better ? ov : rv;
                rn = better ? on : rn;
            }
            if (r == 0) v0max = rv;
            float wr = expf((rv - v0max) * 0.125f);
            wsum += wr;
            if (lane == 0) { wr_l[wv*TOPK + r] = wr; tn_l[wv*TOPK + r] = rn; }
            if ((rn & 63) == lane) { taken |= 1u << (rn >> 6); need = true; }
            parr[r] = fmaxf(vpae[(size_t)rn*FF + lane] + pp, 0.f);
        }
        /* pack p -> LDS, XOR slot swizzle vs 32-way conflict */
#pragma unroll
        for (int q = 0; q < 4; ++q) {
            int slot = q ^ (lane & 3);
            float4 o; o.x = parr[4*q]; o.y = parr[4*q+1]; o.z = parr[4*q+2]; o.w = parr[4*q+3];
            *(float4*)&plw[lane*16 + slot*4] = o;
        }
        /* adapter layer 2 in regs */
        float a2[16];
#pragma unroll
        for (int r = 0; r < 16; ++r) a2[r] = ab1v;
#pragma unroll 1
        for (int j4 = 0; j4 < 16; ++j4) {
            const float* plj = &plw[j4*64];
#pragma unroll
            for (int jj = 0; jj < 4; ++jj) {
                float w = w1p[(4*j4+jj)*FF + lane];
#pragma unroll
                for (int lq = 0; lq < 4; ++lq) {
                    float4 d = *(const float4*)&plj[jj*16 + ((lq ^ jj) * 4)];
                    a2[4*lq+0] = fmaf(d.x, w, a2[4*lq+0]);
                    a2[4*lq+1] = fmaf(d.y, w, a2[4*lq+1]);
                    a2[4*lq+2] = fmaf(d.z, w, a2[4*lq+2]);
                    a2[4*lq+3] = fmaf(d.w, w, a2[4*lq+3]);
                }
            }
        }
        /* LN + residual + attn-weighted sum */
        float outacc = 0.f;
#pragma unroll
        for (int r = 0; r < TOPK; ++r) {
            float av = a2[r];
            float sm = av, s2 = av*av;
            wred_sum2(sm, s2);
            float mean = sm * (1.f/64.f);
            float var = s2 * (1.f/64.f) - mean*mean;
            float lnv = (av - mean) * rsqrtf(var + 1e-5f) * agv + abv;
            int n = tn_l[wv*TOPK + r];
            float vt = vpe[(size_t)n*FF + lane];
            outacc = fmaf(wr_l[wv*TOPK + r], vt + lnv, outacc);
        }
        float res = outacc / wsum + smlp_r[u];
        if (base + s < cnt) eo[(size_t)entry*FF + lane] = res;
    }
}

/* ------------ K4: combine + final MLP (16 samples / 256 thr) ------------ */
__global__ __launch_bounds__(256) void k_final(
    const float* __restrict__ eo, const float* __restrict__ rw,
    const float* __restrict__ fw0, const float* __restrict__ fb0,
    const float* __restrict__ fw1, const float* __restrict__ fb1,
    const float* __restrict__ fw2, const float* __restrict__ fb2,
    const float* __restrict__ fw3, const float* __restrict__ fb3,
    float* __restrict__ refined)
{
    __shared__ float sh[16*HH];       /* 16KB */
    const int tid = threadIdx.x, lane = tid & 63, wv = tid >> 6;
    const int sbase = blockIdx.x * 16;
    const int r0 = wv*4;
    for (int i = tid; i < 16*64; i += 256) {
        int s = i >> 6, c = i & 63;
        int b = sbase + s;
        sh[s*HH + c] = rw[b*2]*eo[(size_t)(b*2)*FF + c]
                     + rw[b*2+1]*eo[(size_t)(b*2+1)*FF + c];
    }
    __syncthreads();
    float acc[4][4];
    /* L0: 64 -> 256 relu */
    {
#pragma unroll
        for (int s = 0; s < 4; ++s)
#pragma unroll
            for (int j = 0; j < 4; ++j) acc[s][j] = 0.f;
#pragma unroll 1
        for (int k = 0; k < 64; ++k) {
            float4 w4 = *(const float4*)&fw0[k*HH + 4*lane];
#pragma unroll
            for (int s = 0; s < 4; ++s) {
                float hv = sh[(r0+s)*HH + k];
                acc[s][0] = fmaf(hv, w4.x, acc[s][0]);
                acc[s][1] = fmaf(hv, w4.y, acc[s][1]);
                acc[s][2] = fmaf(hv, w4.z, acc[s][2]);
                acc[s][3] = fmaf(hv, w4.w, acc[s][3]);
            }
        }
        float4 b4 = *(const float4*)&fb0[4*lane];
#pragma unroll
        for (int s = 0; s < 4; ++s) {
            float4 o;
            o.x = fmaxf(acc[s][0] + b4.x, 0.f);
            o.y = fmaxf(acc[s][1] + b4.y, 0.f);
            o.z = fmaxf(acc[s][2] + b4.z, 0.f);
            o.w = fmaxf(acc[s][3] + b4.w, 0.f);
            *(float4*)&sh[(r0+s)*HH + 4*lane] = o;
        }
    }
    /* L1, L2: 256 -> 256 relu */
#pragma unroll 1
    for (int layer = 0; layer < 2; ++layer) {
        const float* W  = layer ? fw2 : fw1;
        const float* bi = layer ? fb2 : fb1;
#pragma unroll
        for (int s = 0; s < 4; ++s)
#pragma unroll
            for (int j = 0; j < 4; ++j) acc[s][j] = 0.f;
#pragma unroll 1
        for (int k4 = 0; k4 < 64; ++k4) {
            float4 h4[4];
#pragma unroll
            for (int s = 0; s < 4; ++s)
                h4[s] = *(const float4*)&sh[(r0+s)*HH + 4*k4];
#pragma unroll
            for (int kk = 0; kk < 4; ++kk) {
                float4 w4 = *(const float4*)&W[(4*k4+kk)*HH + 4*lane];
#pragma unroll
                for (int s = 0; s < 4; ++s) {
                    float hv = (kk==0)?h4[s].x:((kk==1)?h4[s].y:((kk==2)?h4[s].z:h4[s].w));
                    acc[s][0] = fmaf(hv, w4.x, acc[s][0]);
                    acc[s][1] = fmaf(hv, w4.y, acc[s][1]);
                    acc[s][2] = fmaf(hv, w4.z, acc[s][2]);
                    acc[s][3] = fmaf(hv, w4.w, acc[s][3]);
                }
            }
        }
        float4 b4 = *(const float4*)&bi[4*lane];
#pragma unroll
        for (int s = 0; s < 4; ++s) {
            float4 o;
            o.x = fmaxf(acc[s][0] + b4.x, 0.f);
            o.y = fmaxf(acc[s][1] + b4.y, 0.f);
            o.z = fmaxf(acc[s][2] + b4.z, 0.f);
            o.w = fmaxf(acc[s][3] + b4.w, 0.f);
            *(float4*)&sh[(r0+s)*HH + 4*lane] = o;
        }
    }
    /* L3: 256 -> 1, sigmoid */
    {
        float4 w4 = *(const float4*)&fw3[4*lane];
#pragma unroll 1
        for (int s = 0; s < 4; ++s) {
            float4 h4 = *(const float4*)&sh[(r0+s)*HH + 4*lane];
            float part = h4.x*w4.x + h4.y*w4.y + h4.z*w4.z + h4.w*w4.w;
            float tot = wred_sum(part) + fb3[0];
            float r = 1.f/(1.f + expf(-tot));
            if (lane == 0) refined[sbase + r0 + s] = r;
        }
    }
}

extern "C" void kernel_launch(void* const* d_in, const int* in_sizes, int n_in,
                              void* d_out, int out_size, void* d_ws, size_t ws_size,
                              hipStream_t stream)
{
    const float* x      = (const float*)d_in[0];
    const float* lines  = (const float*)d_in[1];
    const float* mem_k  = (const float*)d_in[2];
    const float* mem_v  = (const float*)d_in[3];
    const float* enc_w0 = (const float*)d_in[4];
    const float* enc_b0 = (const float*)d_in[5];
    const float* enc_wh = (const float*)d_in[6];
    const float* enc_bh = (const float*)d_in[7];
    const float* enc_wo = (const float*)d_in[8];
    const float* enc_bo = (const float*)d_in[9];
    const float* ln_g   = (const float*)d_in[10];
    const float* ln_b   = (const float*)d_in[11];
    const float* wq     = (const float*)d_in[12];
    const float* wk     = (const float*)d_in[13];
    const float* wv_    = (const float*)d_in[14];
    const float* ad_w0  = (const float*)d_in[15];
    const float* ad_b0  = (const float*)d_in[16];
    const float* ad_w1  = (const float*)d_in[17];
    const float* ad_b1  = (const float*)d_in[18];
    const float* ad_g   = (const float*)d_in[19];
    const float* ad_b   = (const float*)d_in[20];
    const float* mg_w0  = (const float*)d_in[21];
    const float* mg_b0  = (const float*)d_in[22];
    const float* mg_w1  = (const float*)d_in[23];
    const float* mg_b1  = (const float*)d_in[24];
    const float* fw0    = (const float*)d_in[25];
    const float* fb0    = (const float*)d_in[26];
    const float* fw1    = (const float*)d_in[27];
    const float* fb1    = (const float*)d_in[28];
    const float* fw2    = (const float*)d_in[29];
    const float* fb2    = (const float*)d_in[30];
    const float* fw3    = (const float*)d_in[31];
    const float* fb3    = (const float*)d_in[32];

    float* out_ref = (float*)d_out;           /* refined: B */
    float* out_rq  = (float*)d_out + BB;      /* raw_q: B*4 */

    float* ws  = (float*)d_ws;
    float* kp  = ws + OFF_KP;
    float* vp  = ws + OFF_VP;
    float* vpa = ws + OFF_VPA;
    float* pe  = ws + OFF_PE;
    float* pfm = ws + OFF_PF;
    float* eo  = ws + OFF_EO;
    float* rw  = ws + OFF_RW;
    float* wpw = ws + OFF_WP;                 /* aliases eo head; consumed before eo written */
    int*  cnts = (int*)(ws + OFF_CNT);
    int*  lst  = (int*)(ws + OFF_LIST);

    hipMemsetAsync(cnts, 0, EE*sizeof(int), stream);
    k_prep<<<dim3(EE), dim3(256), 0, stream>>>(wv_, ad_w0, wpw);
    k_proj<<<dim3(EE*64), dim3(256), 0, stream>>>(mem_k, mem_v, wk, wv_, wpw, kp, vp, vpa);
    k_route<<<dim3(BB/256), dim3(256), 0, stream>>>(x, lines, mg_w0, mg_b0, mg_w1, mg_b1,
                                                    pe, pfm, out_rq, rw, cnts, lst);
    k_expert<<<dim3(NBX, EE), dim3(512), 0, stream>>>(pe, pfm, kp, vp, vpa,
        enc_w0, enc_b0, enc_wh, enc_bh, enc_wo, enc_bo, ln_g, ln_b, wq,
        ad_w0, ad_b0, ad_w1, ad_b1, ad_g, ad_b, cnts, lst, eo);
    k_final<<<dim3(BB/16), dim3(256), 0, stream>>>(eo, rw, fw0, fb0, fw1, fb1,
                                                   fw2, fb2, fw3, fb3, out_ref);
}

// Round 3
// 1484.649 us; speedup vs baseline: 2.1870x; 2.1870x over previous
//
#include <hip/hip_runtime.h>
#include <math.h>

#define EE 4
#define BB 16384
#define NN 1024
#define FF 64
#define HH 256
#define PED 63
#define TOPK 16
#define LINE 64
#define TS 32
#define NBX (BB/TS)   /* 512 */

/* workspace offsets (floats) */
#define OFF_KP   0u
#define OFF_VP   262144u
#define OFF_VPA  524288u
#define OFF_PE   786432u
#define OFF_PF   1818624u
#define OFF_EO   2867200u      /* 2*B*64 ; WP aliases its head (read before EO written) */
#define OFF_RW   4964352u
#define OFF_CNT  4997120u
#define OFF_LIST 4997128u
#define OFF_WP   OFF_EO

__device__ __forceinline__ float wred_sum(float v) {
#pragma unroll
    for (int off = 32; off > 0; off >>= 1) v += __shfl_xor(v, off, 64);
    return v;
}
__device__ __forceinline__ void wred_sum2(float& a, float& b) {
#pragma unroll
    for (int off = 32; off > 0; off >>= 1) {
        a += __shfl_xor(a, off, 64);
        b += __shfl_xor(b, off, 64);
    }
}

/* ------------ K0: wp[e] = wv[e] @ ad_w0[e][:64] ------------ */
__global__ __launch_bounds__(256) void k_prep(
    const float* __restrict__ wv, const float* __restrict__ aw0,
    float* __restrict__ wp)
{
    int e = blockIdx.x;
    __shared__ float sa[FF*FF];
    for (int i = threadIdx.x; i < FF*FF; i += 256)
        sa[i] = aw0[(size_t)e*128*FF + i];   /* top 64 rows */
    __syncthreads();
    int f = threadIdx.x & 63, dg = threadIdx.x >> 6;
    for (int d = dg; d < FF; d += 4) {
        const float* wr = wv + (size_t)e*FF*FF + d*FF;
        float a = 0.f;
        for (int c = 0; c < FF; ++c) a = fmaf(wr[c], sa[c*FF+f], a);
        wp[(size_t)e*FF*FF + d*FF + f] = a;
    }
}

/* ------------ K1: kp = mem_k@wk, vp = mem_v@wv, vpa = mem_v@wp ------------ */
__global__ __launch_bounds__(256) void k_proj(
    const float* __restrict__ mem_k, const float* __restrict__ mem_v,
    const float* __restrict__ wk, const float* __restrict__ wv,
    const float* __restrict__ wp,
    float* __restrict__ kp, float* __restrict__ vp, float* __restrict__ vpa)
{
    int e = blockIdx.x >> 6;          /* E*64 blocks, 16 rows each */
    int nbase = (blockIdx.x & 63) * 16;
    __shared__ float swk[FF*FF], swv[FF*FF], swp[FF*FF];
    for (int i = threadIdx.x; i < FF*FF; i += 256) {
        swk[i] = wk[(size_t)e*FF*FF + i];
        swv[i] = wv[(size_t)e*FF*FF + i];
        swp[i] = wp[(size_t)e*FF*FF + i];
    }
    __syncthreads();
    int r4 = threadIdx.x >> 6;
    int f  = threadIdx.x & 63;
#pragma unroll 1
    for (int it = 0; it < 4; ++it) {
        int n = nbase + it*4 + r4;
        const float* mk = mem_k + ((size_t)e*NN + n)*FF;
        const float* mv = mem_v + ((size_t)e*NN + n)*FF;
        float ak = 0.f, av = 0.f, aa = 0.f;
#pragma unroll 1
        for (int c4 = 0; c4 < 16; ++c4) {
            float4 k4 = *(const float4*)&mk[4*c4];
            float4 v4 = *(const float4*)&mv[4*c4];
#pragma unroll
            for (int kk = 0; kk < 4; ++kk) {
                float mkc = (kk==0)?k4.x:((kk==1)?k4.y:((kk==2)?k4.z:k4.w));
                float mvc = (kk==0)?v4.x:((kk==1)?v4.y:((kk==2)?v4.z:v4.w));
                int c = 4*c4 + kk;
                ak = fmaf(mkc, swk[c*FF+f], ak);
                av = fmaf(mvc, swv[c*FF+f], av);
                aa = fmaf(mvc, swp[c*FF+f], aa);
            }
        }
        kp [((size_t)e*NN+n)*FF + f] = ak;
        vp [((size_t)e*NN+n)*FF + f] = av;
        vpa[((size_t)e*NN+n)*FF + f] = aa;
    }
}

/* ------------ K2: routing + positional enc + param feats ------------ */
__global__ __launch_bounds__(256) void k_route(
    const float* __restrict__ x, const float* __restrict__ lines,
    const float* __restrict__ mg_w0, const float* __restrict__ mg_b0,
    const float* __restrict__ mg_w1, const float* __restrict__ mg_b1,
    float* __restrict__ pe_x, float* __restrict__ pfm,
    float* __restrict__ rawq, float* __restrict__ rw,
    int* __restrict__ counts, int* __restrict__ lists)
{
    __shared__ float slines[LINE*LINE];
    for (int i = threadIdx.x; i < LINE*LINE; i += 256) slines[i] = lines[i];
    __syncthreads();
    int b = blockIdx.x*256 + threadIdx.x;
    float4 xx = ((const float4*)x)[b];
    float c0 = xx.x, c1 = xx.y, c2 = xx.z, c3 = xx.w;

    float p = c3 * (float)(LINE-1);
    float pfl = floorf(p);
    float w = p - pfl;
    int il = (int)pfl;
    int ih = (int)fminf(fmaxf(pfl + 1.f, 0.f), (float)(LINE-1));
    for (int c = 0; c < FF; ++c) {
        float lo = slines[c*LINE+il], hi = slines[c*LINE+ih];
        pfm[(size_t)b*FF + c] = lo + w*(hi-lo);
    }
    float* pe = pe_x + (size_t)b*PED;
    pe[0]=c0; pe[1]=c1; pe[2]=c2;
    const float PI = 3.14159265358979323846f;
    float coords[3] = {c0,c1,c2};
#pragma unroll
    for (int cc = 0; cc < 3; ++cc) {
        float fr = PI;
        for (int k = 0; k < 10; ++k) {
            float s = coords[cc]*fr;
            pe[3 + cc*20 + k*2 + 0] = sinf(s);
            pe[3 + cc*20 + k*2 + 1] = cosf(s);
            fr *= 2.f;
        }
    }
    float acc[4] = {mg_b1[0], mg_b1[1], mg_b1[2], mg_b1[3]};
    for (int j = 0; j < 64; ++j) {
        float h = fmaf(c0, mg_w0[j], fmaf(c1, mg_w0[64+j], fmaf(c2, mg_w0[128+j], mg_b0[j])));
        h = fmaxf(h, 0.f);
#pragma unroll
        for (int e4 = 0; e4 < 4; ++e4) acc[e4] = fmaf(h, mg_w1[j*4+e4], acc[e4]);
    }
#pragma unroll
    for (int e4 = 0; e4 < 4; ++e4) rawq[(size_t)b*4 + e4] = acc[e4];
    float m = fmaxf(fmaxf(acc[0],acc[1]), fmaxf(acc[2],acc[3]));
    float ex[4], den = 0.f;
#pragma unroll
    for (int e4 = 0; e4 < 4; ++e4) { ex[e4] = expf(acc[e4]-m); den += ex[e4]; }
    float pr[4];
#pragma unroll
    for (int e4 = 0; e4 < 4; ++e4) pr[e4] = fmaxf(ex[e4]/den, 1e-8f);
    int i0 = 0;
#pragma unroll
    for (int e4 = 1; e4 < 4; ++e4) if (pr[e4] > pr[i0]) i0 = e4;
    int i1 = -1;
#pragma unroll
    for (int e4 = 0; e4 < 4; ++e4) {
        if (e4 == i0) continue;
        if (i1 < 0 || pr[e4] > pr[i1]) i1 = e4;
    }
    float vs = pr[i0] + pr[i1];
    rw[b*2+0] = pr[i0]/vs;
    rw[b*2+1] = pr[i1]/vs;
    int p0 = atomicAdd(&counts[i0], 1);
    lists[i0*BB + p0] = b*2 + 0;
    int p1 = atomicAdd(&counts[i1], 1);
    lists[i1*BB + p1] = b*2 + 1;
}

/* ------------ K3: expert pipeline — 8 waves x 4 samples, LDS-staged weights ------------ */
__global__ __launch_bounds__(512) void k_expert(
    const float* __restrict__ pe_x, const float* __restrict__ pfm,
    const float* __restrict__ kp, const float* __restrict__ vp,
    const float* __restrict__ vpa,
    const float* __restrict__ enc_w0, const float* __restrict__ enc_b0,
    const float* __restrict__ enc_wh, const float* __restrict__ enc_bh,
    const float* __restrict__ enc_wo, const float* __restrict__ enc_bo,
    const float* __restrict__ ln_g, const float* __restrict__ ln_b,
    const float* __restrict__ wq,
    const float* __restrict__ aw0, const float* __restrict__ ab0,
    const float* __restrict__ aw1, const float* __restrict__ ab1,
    const float* __restrict__ adg, const float* __restrict__ adb,
    const int* __restrict__ counts, const int* __restrict__ lists,
    float* __restrict__ eo)
{
    const int e = blockIdx.y;
    const int base = blockIdx.x * TS;
    const int cnt = counts[e];
    if (base >= cnt) return;

    __shared__ float sh[TS*HH];       /* 32KB: h rows; q in cols 64..127; later pl */
    __shared__ float swt[8192];       /* 32KB: weight tiles / wq / skp[64][68] / a0b+w1p */
    __shared__ float wr_l[8*TOPK];
    __shared__ int   tn_l[8*TOPK];
    __shared__ int   slist[TS];

    const int tid = threadIdx.x;
    const int lane = tid & 63;
    const int wv = tid >> 6;          /* 0..7 */
    const int r0 = wv*4;

    if (tid < TS) {
        int idx = base + tid;
        if (idx >= cnt) idx = cnt - 1;
        slist[tid] = lists[e*BB + idx];
    }
    __syncthreads();
    /* stage pe rows */
    for (int i = tid; i < TS*64; i += 512) {
        int s = i >> 6, j = i & 63;
        int bq = slist[s] >> 1;
        sh[s*HH + j] = (j < PED) ? pe_x[(size_t)bq*PED + j] : 0.f;
    }
    /* no barrier needed yet: first weight-tile stage below barriers before use */

    float acc[4][4];

    /* L0: 63 -> 256, 32-row weight tiles in LDS */
    {
        const float* W = enc_w0 + (size_t)e*PED*HH;
#pragma unroll
        for (int s = 0; s < 4; ++s)
#pragma unroll
            for (int j = 0; j < 4; ++j) acc[s][j] = 0.f;
#pragma unroll 1
        for (int t = 0; t < 2; ++t) {
            int rbase = t*32;
            int rows = (PED - rbase < 32) ? (PED - rbase) : 32;
            int total = rows*HH;
            __syncthreads();
            for (int i = tid*4; i < total; i += 2048)
                *(float4*)&swt[i] = *(const float4*)&W[rbase*HH + i];
            __syncthreads();
#pragma unroll 1
            for (int k = 0; k < rows; ++k) {
                float4 w4 = *(const float4*)&swt[k*HH + 4*lane];
#pragma unroll
                for (int s = 0; s < 4; ++s) {
                    float hv = sh[(r0+s)*HH + rbase + k];
                    acc[s][0] = fmaf(hv, w4.x, acc[s][0]);
                    acc[s][1] = fmaf(hv, w4.y, acc[s][1]);
                    acc[s][2] = fmaf(hv, w4.z, acc[s][2]);
                    acc[s][3] = fmaf(hv, w4.w, acc[s][3]);
                }
            }
        }
        __syncthreads();   /* all waves done reading pe cols before overwrite */
        float4 b4 = *(const float4*)&enc_b0[e*HH + 4*lane];
#pragma unroll
        for (int s = 0; s < 4; ++s) {
            float4 o;
            o.x = sinf(30.0f*(acc[s][0] + b4.x));
            o.y = sinf(30.0f*(acc[s][1] + b4.y));
            o.z = sinf(30.0f*(acc[s][2] + b4.z));
            o.w = sinf(30.0f*(acc[s][3] + b4.w));
            *(float4*)&sh[(r0+s)*HH + 4*lane] = o;
        }
    }

    /* L1, L2: 256 -> 256, 32-row tiles */
#pragma unroll 1
    for (int layer = 0; layer < 2; ++layer) {
        const float* W = enc_wh + ((size_t)(e*2+layer))*HH*HH;
#pragma unroll
        for (int s = 0; s < 4; ++s)
#pragma unroll
            for (int j = 0; j < 4; ++j) acc[s][j] = 0.f;
#pragma unroll 1
        for (int t = 0; t < 8; ++t) {
            __syncthreads();
            for (int i = tid*4; i < 8192; i += 2048)
                *(float4*)&swt[i] = *(const float4*)&W[t*32*HH + i];
            __syncthreads();
#pragma unroll 1
            for (int k4 = 0; k4 < 8; ++k4) {
                float4 h4[4];
#pragma unroll
                for (int s = 0; s < 4; ++s)
                    h4[s] = *(const float4*)&sh[(r0+s)*HH + t*32 + 4*k4];
#pragma unroll
                for (int kk = 0; kk < 4; ++kk) {
                    float4 w4 = *(const float4*)&swt[(4*k4+kk)*HH + 4*lane];
#pragma unroll
                    for (int s = 0; s < 4; ++s) {
                        float hv = (kk==0)?h4[s].x:((kk==1)?h4[s].y:((kk==2)?h4[s].z:h4[s].w));
                        acc[s][0] = fmaf(hv, w4.x, acc[s][0]);
                        acc[s][1] = fmaf(hv, w4.y, acc[s][1]);
                        acc[s][2] = fmaf(hv, w4.z, acc[s][2]);
                        acc[s][3] = fmaf(hv, w4.w, acc[s][3]);
                    }
                }
            }
        }
        __syncthreads();   /* all reads of h done before overwrite */
        float4 b4 = *(const float4*)&enc_bh[(e*2+layer)*HH + 4*lane];
#pragma unroll
        for (int s = 0; s < 4; ++s) {
            float4 o;
            o.x = sinf(30.0f*(acc[s][0] + b4.x));
            o.y = sinf(30.0f*(acc[s][1] + b4.y));
            o.z = sinf(30.0f*(acc[s][2] + b4.z));
            o.w = sinf(30.0f*(acc[s][3] + b4.w));
            *(float4*)&sh[(r0+s)*HH + 4*lane] = o;
        }
    }

    /* out layer: 256 -> 64, 64-row tiles; smlp in regs */
    float smlp_r[4];
    {
        const float* W = enc_wo + (size_t)e*HH*FF;
        float a2o[4] = {0.f,0.f,0.f,0.f};
#pragma unroll 1
        for (int t = 0; t < 4; ++t) {
            __syncthreads();
            for (int i = tid*4; i < 4096; i += 2048)
                *(float4*)&swt[i] = *(const float4*)&W[t*64*FF + i];
            __syncthreads();
#pragma unroll 1
            for (int k4 = 0; k4 < 16; ++k4) {
                float4 h4[4];
#pragma unroll
                for (int s = 0; s < 4; ++s)
                    h4[s] = *(const float4*)&sh[(r0+s)*HH + t*64 + 4*k4];
#pragma unroll
                for (int kk = 0; kk < 4; ++kk) {
                    float w = swt[(4*k4+kk)*FF + lane];
#pragma unroll
                    for (int s = 0; s < 4; ++s) {
                        float hv = (kk==0)?h4[s].x:((kk==1)?h4[s].y:((kk==2)?h4[s].z:h4[s].w));
                        a2o[s] = fmaf(hv, w, a2o[s]);
                    }
                }
            }
        }
        float bv = enc_bo[e*FF + lane];
#pragma unroll
        for (int s = 0; s < 4; ++s) smlp_r[s] = a2o[s] + bv;
    }

    /* stage wq; then LN + q (q -> sh cols 64..127) */
    {
        const float* Wq = wq + (size_t)e*FF*FF;
        __syncthreads();
        for (int i = tid*4; i < 4096; i += 2048)
            *(float4*)&swt[i] = *(const float4*)&Wq[i];
        __syncthreads();
        float g = ln_g[lane], bb2 = ln_b[lane];
#pragma unroll 1
        for (int s = 0; s < 4; ++s) {
            float hv = smlp_r[s];
            float sm = hv, s2 = hv*hv;
            wred_sum2(sm, s2);
            float mean = sm * (1.f/64.f);
            float var = s2 * (1.f/64.f) - mean*mean;
            float lnv = (hv - mean) * rsqrtf(var + 1e-5f) * g + bb2;
            sh[(r0+s)*HH + lane] = lnv;
            float qa = 0.f;
#pragma unroll 1
            for (int c4 = 0; c4 < 16; ++c4) {
                float4 l4 = *(const float4*)&sh[(r0+s)*HH + 4*c4];
                qa = fmaf(l4.x, swt[(4*c4+0)*FF + lane], qa);
                qa = fmaf(l4.y, swt[(4*c4+1)*FF + lane], qa);
                qa = fmaf(l4.z, swt[(4*c4+2)*FF + lane], qa);
                qa = fmaf(l4.w, swt[(4*c4+3)*FF + lane], qa);
            }
            sh[(r0+s)*HH + 64 + lane] = qa;
        }
    }

    /* scores: kp staged per block into swt as [64][68]; lane owns key row c*64+lane */
    float sc[4][16];
    {
        const float* kpe = kp + (size_t)e*NN*FF;
        const int str = tid >> 3;          /* stage row 0..63 */
        const int stc = (tid & 7) * 8;     /* stage col */
#pragma unroll 1
        for (int c = 0; c < 16; ++c) {
            __syncthreads();
            {
                const float* src = kpe + (size_t)(c*64 + str)*FF + stc;
                float* dst = &swt[str*68 + stc];
                *(float4*)(dst+0) = *(const float4*)(src+0);
                *(float4*)(dst+4) = *(const float4*)(src+4);
            }
            __syncthreads();
            float a0 = 0.f, a1 = 0.f, a2s = 0.f, a3 = 0.f;
#pragma unroll
            for (int f4 = 0; f4 < 16; ++f4) {
                float4 k4 = *(const float4*)&swt[lane*68 + 4*f4];
                float4 q0 = *(const float4*)&sh[(r0+0)*HH + 64 + 4*f4];
                float4 q1 = *(const float4*)&sh[(r0+1)*HH + 64 + 4*f4];
                float4 q2 = *(const float4*)&sh[(r0+2)*HH + 64 + 4*f4];
                float4 q3 = *(const float4*)&sh[(r0+3)*HH + 64 + 4*f4];
                a0 = fmaf(k4.x,q0.x,fmaf(k4.y,q0.y,fmaf(k4.z,q0.z,fmaf(k4.w,q0.w,a0))));
                a1 = fmaf(k4.x,q1.x,fmaf(k4.y,q1.y,fmaf(k4.z,q1.z,fmaf(k4.w,q1.w,a1))));
                a2s= fmaf(k4.x,q2.x,fmaf(k4.y,q2.y,fmaf(k4.z,q2.z,fmaf(k4.w,q2.w,a2s))));
                a3 = fmaf(k4.x,q3.x,fmaf(k4.y,q3.y,fmaf(k4.z,q3.z,fmaf(k4.w,q3.w,a3))));
            }
            sc[0][c]=a0; sc[1][c]=a1; sc[2][c]=a2s; sc[3][c]=a3;
        }
    }

    /* stage a0b (bottom half of ad_w0) + w1p (aw1) into swt[0..4095] / [4096..8191] */
    __syncthreads();
    {
        const float* a0bG = aw0 + ((size_t)e*128 + 64)*FF;
        const float* w1G  = aw1 + (size_t)e*FF*FF;
        for (int i = tid*4; i < 4096; i += 2048) {
            *(float4*)&swt[i]        = *(const float4*)&a0bG[i];
            *(float4*)&swt[4096 + i] = *(const float4*)&w1G[i];
        }
    }
    __syncthreads();

    /* top-16 + adapter, per sample; pl = wave's own sh rows (h/q dead) */
    const float* vpe  = vp  + (size_t)e*NN*FF;
    const float* vpae = vpa + (size_t)e*NN*FF;
    const float agv = adg[e*FF + lane], abv = adb[e*FF + lane];
    const float ab1v = ab1[e*FF + lane];
    float* plw = &sh[r0*HH];          /* 1024 floats, wave-private */

#pragma unroll 1
    for (int u = 0; u < 4; ++u) {
        int s = r0 + u;
        int entry = slist[s];
        int bq = entry >> 1;
        float sc_cur[16];
#pragma unroll
        for (int c = 0; c < 16; ++c)
            sc_cur[c] = (u==0)?sc[0][c]:((u==1)?sc[1][c]:((u==2)?sc[2][c]:sc[3][c]));

        /* pf half of adapter layer 1 (weights in LDS) */
        float pp = ab0[e*FF + lane];
        {
            const float* pfr = pfm + (size_t)bq*FF;
#pragma unroll 1
            for (int c4 = 0; c4 < 16; ++c4) {
                float4 p4 = *(const float4*)&pfr[4*c4];
                pp = fmaf(p4.x, swt[(4*c4+0)*FF + lane], pp);
                pp = fmaf(p4.y, swt[(4*c4+1)*FF + lane], pp);
                pp = fmaf(p4.z, swt[(4*c4+2)*FF + lane], pp);
                pp = fmaf(p4.w, swt[(4*c4+3)*FF + lane], pp);
            }
        }

        unsigned taken = 0u;
        bool need = true;
        float bv = -1e30f; int bn = 0x7fffffff;
        float v0max = 0.f, wsum = 0.f;
        float parr[16];
#pragma unroll
        for (int r = 0; r < TOPK; ++r) {
            if (need) {
                bv = -1e30f; bn = 0x7fffffff;
#pragma unroll
                for (int c = 0; c < 16; ++c) {
                    float v = sc_cur[c];
                    int n = c*64 + lane;
                    bool ok = !((taken >> c) & 1u);
                    bool better = ok && (v > bv || (v == bv && n < bn));
                    bv = better ? v : bv;
                    bn = better ? n : bn;
                }
                need = false;
            }
            float rv = bv; int rn = bn;
#pragma unroll
            for (int off = 32; off > 0; off >>= 1) {
                float ov = __shfl_xor(rv, off, 64);
                int on = __shfl_xor(rn, off, 64);
                bool better = (ov > rv) || (ov == rv && on < rn);
                rv = better ? ov : rv;
                rn = better ? on : rn;
            }
            if (r == 0) v0max = rv;
            float wr = expf((rv - v0max) * 0.125f);
            wsum += wr;
            if (lane == 0) { wr_l[wv*TOPK + r] = wr; tn_l[wv*TOPK + r] = rn; }
            if ((rn & 63) == lane) { taken |= 1u << (rn >> 6); need = true; }
            parr[r] = fmaxf(vpae[(size_t)rn*FF + lane] + pp, 0.f);
        }
        /* pack p -> LDS, XOR slot swizzle vs 32-way conflict */
#pragma unroll
        for (int q = 0; q < 4; ++q) {
            int slot = q ^ (lane & 3);
            float4 o; o.x = parr[4*q]; o.y = parr[4*q+1]; o.z = parr[4*q+2]; o.w = parr[4*q+3];
            *(float4*)&plw[lane*16 + slot*4] = o;
        }
        /* adapter layer 2 in regs (weights in LDS at swt+4096) */
        float a2[16];
#pragma unroll
        for (int r = 0; r < 16; ++r) a2[r] = ab1v;
#pragma unroll 1
        for (int j4 = 0; j4 < 16; ++j4) {
            const float* plj = &plw[j4*64];
#pragma unroll
            for (int jj = 0; jj < 4; ++jj) {
                float w = swt[4096 + (4*j4+jj)*FF + lane];
#pragma unroll
                for (int lq = 0; lq < 4; ++lq) {
                    float4 d = *(const float4*)&plj[jj*16 + ((lq ^ jj) * 4)];
                    a2[4*lq+0] = fmaf(d.x, w, a2[4*lq+0]);
                    a2[4*lq+1] = fmaf(d.y, w, a2[4*lq+1]);
                    a2[4*lq+2] = fmaf(d.z, w, a2[4*lq+2]);
                    a2[4*lq+3] = fmaf(d.w, w, a2[4*lq+3]);
                }
            }
        }
        /* LN + residual + attn-weighted sum */
        float outacc = 0.f;
#pragma unroll
        for (int r = 0; r < TOPK; ++r) {
            float av = a2[r];
            float sm = av, s2 = av*av;
            wred_sum2(sm, s2);
            float mean = sm * (1.f/64.f);
            float var = s2 * (1.f/64.f) - mean*mean;
            float lnv = (av - mean) * rsqrtf(var + 1e-5f) * agv + abv;
            int n = tn_l[wv*TOPK + r];
            float vt = vpe[(size_t)n*FF + lane];
            outacc = fmaf(wr_l[wv*TOPK + r], vt + lnv, outacc);
        }
        float res = outacc / wsum + smlp_r[u];
        if (base + s < cnt) eo[(size_t)entry*FF + lane] = res;
    }
}

/* ------------ K4: combine + final MLP (16 samples / 256 thr) ------------ */
__global__ __launch_bounds__(256) void k_final(
    const float* __restrict__ eo, const float* __restrict__ rw,
    const float* __restrict__ fw0, const float* __restrict__ fb0,
    const float* __restrict__ fw1, const float* __restrict__ fb1,
    const float* __restrict__ fw2, const float* __restrict__ fb2,
    const float* __restrict__ fw3, const float* __restrict__ fb3,
    float* __restrict__ refined)
{
    __shared__ float sh[16*HH];       /* 16KB */
    const int tid = threadIdx.x, lane = tid & 63, wv = tid >> 6;
    const int sbase = blockIdx.x * 16;
    const int r0 = wv*4;
    for (int i = tid; i < 16*64; i += 256) {
        int s = i >> 6, c = i & 63;
        int b = sbase + s;
        sh[s*HH + c] = rw[b*2]*eo[(size_t)(b*2)*FF + c]
                     + rw[b*2+1]*eo[(size_t)(b*2+1)*FF + c];
    }
    __syncthreads();
    float acc[4][4];
    /* L0: 64 -> 256 relu */
    {
#pragma unroll
        for (int s = 0; s < 4; ++s)
#pragma unroll
            for (int j = 0; j < 4; ++j) acc[s][j] = 0.f;
#pragma unroll 1
        for (int k = 0; k < 64; ++k) {
            float4 w4 = *(const float4*)&fw0[k*HH + 4*lane];
#pragma unroll
            for (int s = 0; s < 4; ++s) {
                float hv = sh[(r0+s)*HH + k];
                acc[s][0] = fmaf(hv, w4.x, acc[s][0]);
                acc[s][1] = fmaf(hv, w4.y, acc[s][1]);
                acc[s][2] = fmaf(hv, w4.z, acc[s][2]);
                acc[s][3] = fmaf(hv, w4.w, acc[s][3]);
            }
        }
        float4 b4 = *(const float4*)&fb0[4*lane];
#pragma unroll
        for (int s = 0; s < 4; ++s) {
            float4 o;
            o.x = fmaxf(acc[s][0] + b4.x, 0.f);
            o.y = fmaxf(acc[s][1] + b4.y, 0.f);
            o.z = fmaxf(acc[s][2] + b4.z, 0.f);
            o.w = fmaxf(acc[s][3] + b4.w, 0.f);
            *(float4*)&sh[(r0+s)*HH + 4*lane] = o;
        }
    }
    /* L1, L2: 256 -> 256 relu */
#pragma unroll 1
    for (int layer = 0; layer < 2; ++layer) {
        const float* W  = layer ? fw2 : fw1;
        const float* bi = layer ? fb2 : fb1;
#pragma unroll
        for (int s = 0; s < 4; ++s)
#pragma unroll
            for (int j = 0; j < 4; ++j) acc[s][j] = 0.f;
#pragma unroll 1
        for (int k4 = 0; k4 < 64; ++k4) {
            float4 h4[4];
#pragma unroll
            for (int s = 0; s < 4; ++s)
                h4[s] = *(const float4*)&sh[(r0+s)*HH + 4*k4];
#pragma unroll
            for (int kk = 0; kk < 4; ++kk) {
                float4 w4 = *(const float4*)&W[(4*k4+kk)*HH + 4*lane];
#pragma unroll
                for (int s = 0; s < 4; ++s) {
                    float hv = (kk==0)?h4[s].x:((kk==1)?h4[s].y:((kk==2)?h4[s].z:h4[s].w));
                    acc[s][0] = fmaf(hv, w4.x, acc[s][0]);
                    acc[s][1] = fmaf(hv, w4.y, acc[s][1]);
                    acc[s][2] = fmaf(hv, w4.z, acc[s][2]);
                    acc[s][3] = fmaf(hv, w4.w, acc[s][3]);
                }
            }
        }
        float4 b4 = *(const float4*)&bi[4*lane];
#pragma unroll
        for (int s = 0; s < 4; ++s) {
            float4 o;
            o.x = fmaxf(acc[s][0] + b4.x, 0.f);
            o.y = fmaxf(acc[s][1] + b4.y, 0.f);
            o.z = fmaxf(acc[s][2] + b4.z, 0.f);
            o.w = fmaxf(acc[s][3] + b4.w, 0.f);
            *(float4*)&sh[(r0+s)*HH + 4*lane] = o;
        }
    }
    /* L3: 256 -> 1, sigmoid */
    {
        float4 w4 = *(const float4*)&fw3[4*lane];
#pragma unroll 1
        for (int s = 0; s < 4; ++s) {
            float4 h4 = *(const float4*)&sh[(r0+s)*HH + 4*lane];
            float part = h4.x*w4.x + h4.y*w4.y + h4.z*w4.z + h4.w*w4.w;
            float tot = wred_sum(part) + fb3[0];
            float r = 1.f/(1.f + expf(-tot));
            if (lane == 0) refined[sbase + r0 + s] = r;
        }
    }
}

extern "C" void kernel_launch(void* const* d_in, const int* in_sizes, int n_in,
                              void* d_out, int out_size, void* d_ws, size_t ws_size,
                              hipStream_t stream)
{
    const float* x      = (const float*)d_in[0];
    const float* lines  = (const float*)d_in[1];
    const float* mem_k  = (const float*)d_in[2];
    const float* mem_v  = (const float*)d_in[3];
    const float* enc_w0 = (const float*)d_in[4];
    const float* enc_b0 = (const float*)d_in[5];
    const float* enc_wh = (const float*)d_in[6];
    const float* enc_bh = (const float*)d_in[7];
    const float* enc_wo = (const float*)d_in[8];
    const float* enc_bo = (const float*)d_in[9];
    const float* ln_g   = (const float*)d_in[10];
    const float* ln_b   = (const float*)d_in[11];
    const float* wq     = (const float*)d_in[12];
    const float* wk     = (const float*)d_in[13];
    const float* wv_    = (const float*)d_in[14];
    const float* ad_w0  = (const float*)d_in[15];
    const float* ad_b0  = (const float*)d_in[16];
    const float* ad_w1  = (const float*)d_in[17];
    const float* ad_b1  = (const float*)d_in[18];
    const float* ad_g   = (const float*)d_in[19];
    const float* ad_b   = (const float*)d_in[20];
    const float* mg_w0  = (const float*)d_in[21];
    const float* mg_b0  = (const float*)d_in[22];
    const float* mg_w1  = (const float*)d_in[23];
    const float* mg_b1  = (const float*)d_in[24];
    const float* fw0    = (const float*)d_in[25];
    const float* fb0    = (const float*)d_in[26];
    const float* fw1    = (const float*)d_in[27];
    const float* fb1    = (const float*)d_in[28];
    const float* fw2    = (const float*)d_in[29];
    const float* fb2    = (const float*)d_in[30];
    const float* fw3    = (const float*)d_in[31];
    const float* fb3    = (const float*)d_in[32];

    float* out_ref = (float*)d_out;           /* refined: B */
    float* out_rq  = (float*)d_out + BB;      /* raw_q: B*4 */

    float* ws  = (float*)d_ws;
    float* kp  = ws + OFF_KP;
    float* vp  = ws + OFF_VP;
    float* vpa = ws + OFF_VPA;
    float* pe  = ws + OFF_PE;
    float* pfm = ws + OFF_PF;
    float* eo  = ws + OFF_EO;
    float* rw  = ws + OFF_RW;
    float* wpw = ws + OFF_WP;                 /* aliases eo head; consumed before eo written */
    int*  cnts = (int*)(ws + OFF_CNT);
    int*  lst  = (int*)(ws + OFF_LIST);

    hipMemsetAsync(cnts, 0, EE*sizeof(int), stream);
    k_prep<<<dim3(EE), dim3(256), 0, stream>>>(wv_, ad_w0, wpw);
    k_proj<<<dim3(EE*64), dim3(256), 0, stream>>>(mem_k, mem_v, wk, wv_, wpw, kp, vp, vpa);
    k_route<<<dim3(BB/256), dim3(256), 0, stream>>>(x, lines, mg_w0, mg_b0, mg_w1, mg_b1,
                                                    pe, pfm, out_rq, rw, cnts, lst);
    k_expert<<<dim3(NBX, EE), dim3(512), 0, stream>>>(pe, pfm, kp, vp, vpa,
        enc_w0, enc_b0, enc_wh, enc_bh, enc_wo, enc_bo, ln_g, ln_b, wq,
        ad_w0, ad_b0, ad_w1, ad_b1, ad_g, ad_b, cnts, lst, eo);
    k_final<<<dim3(BB/16), dim3(256), 0, stream>>>(eo, rw, fw0, fb0, fw1, fb1,
                                                   fw2, fb2, fw3, fb3, out_ref);
}

// Round 4
// 1224.879 us; speedup vs baseline: 2.6508x; 1.2121x over previous
//
#include <hip/hip_runtime.h>
#include <math.h>

#define EE 4
#define BB 16384
#define NN 1024
#define FF 64
#define HH 256
#define PED 63
#define TOPK 16
#define LINE 64
#define TS 32
#define NBX (BB/TS)   /* 512 */

/* workspace offsets (floats) — total ~9.26M floats ~= 37 MB */
#define OFF_KP   0u
#define OFF_VP   262144u
#define OFF_VPA  524288u
#define OFF_PE   786432u       /* B*63 */
#define OFF_PF   1818624u      /* B*64 */
#define OFF_EO   2867200u      /* 2*B*64 ; WP aliases head (read before EO written) */
#define OFF_RW   4964352u
#define OFF_CNT  4997120u
#define OFF_LIST 4997128u      /* E*B ints */
#define OFF_QV   5062664u      /* 2*B*64, indexed by entry */
#define OFF_SM   7159816u      /* 2*B*64, indexed by entry */
#define OFF_WP   OFF_EO

__device__ __forceinline__ float wred_sum(float v) {
#pragma unroll
    for (int off = 32; off > 0; off >>= 1) v += __shfl_xor(v, off, 64);
    return v;
}
__device__ __forceinline__ void wred_sum2(float& a, float& b) {
#pragma unroll
    for (int off = 32; off > 0; off >>= 1) {
        a += __shfl_xor(a, off, 64);
        b += __shfl_xor(b, off, 64);
    }
}

/* ------------ K0: wp[e] = wv[e] @ ad_w0[e][:64] ------------ */
__global__ __launch_bounds__(256) void k_prep(
    const float* __restrict__ wv, const float* __restrict__ aw0,
    float* __restrict__ wp)
{
    int e = blockIdx.x;
    __shared__ float sa[FF*FF];
    for (int i = threadIdx.x; i < FF*FF; i += 256)
        sa[i] = aw0[(size_t)e*128*FF + i];
    __syncthreads();
    int f = threadIdx.x & 63, dg = threadIdx.x >> 6;
    for (int d = dg; d < FF; d += 4) {
        const float* wr = wv + (size_t)e*FF*FF + d*FF;
        float a = 0.f;
        for (int c = 0; c < FF; ++c) a = fmaf(wr[c], sa[c*FF+f], a);
        wp[(size_t)e*FF*FF + d*FF + f] = a;
    }
}

/* ------------ K1: kp = mem_k@wk, vp = mem_v@wv, vpa = mem_v@wp ------------ */
__global__ __launch_bounds__(256) void k_proj(
    const float* __restrict__ mem_k, const float* __restrict__ mem_v,
    const float* __restrict__ wk, const float* __restrict__ wv,
    const float* __restrict__ wp,
    float* __restrict__ kp, float* __restrict__ vp, float* __restrict__ vpa)
{
    int e = blockIdx.x >> 6;
    int nbase = (blockIdx.x & 63) * 16;
    __shared__ float swk[FF*FF], swv[FF*FF], swp[FF*FF];
    for (int i = threadIdx.x; i < FF*FF; i += 256) {
        swk[i] = wk[(size_t)e*FF*FF + i];
        swv[i] = wv[(size_t)e*FF*FF + i];
        swp[i] = wp[(size_t)e*FF*FF + i];
    }
    __syncthreads();
    int r4 = threadIdx.x >> 6;
    int f  = threadIdx.x & 63;
#pragma unroll 1
    for (int it = 0; it < 4; ++it) {
        int n = nbase + it*4 + r4;
        const float* mk = mem_k + ((size_t)e*NN + n)*FF;
        const float* mv = mem_v + ((size_t)e*NN + n)*FF;
        float ak = 0.f, av = 0.f, aa = 0.f;
#pragma unroll 1
        for (int c4 = 0; c4 < 16; ++c4) {
            float4 k4 = *(const float4*)&mk[4*c4];
            float4 v4 = *(const float4*)&mv[4*c4];
#pragma unroll
            for (int kk = 0; kk < 4; ++kk) {
                float mkc = (kk==0)?k4.x:((kk==1)?k4.y:((kk==2)?k4.z:k4.w));
                float mvc = (kk==0)?v4.x:((kk==1)?v4.y:((kk==2)?v4.z:v4.w));
                int c = 4*c4 + kk;
                ak = fmaf(mkc, swk[c*FF+f], ak);
                av = fmaf(mvc, swv[c*FF+f], av);
                aa = fmaf(mvc, swp[c*FF+f], aa);
            }
        }
        kp [((size_t)e*NN+n)*FF + f] = ak;
        vp [((size_t)e*NN+n)*FF + f] = av;
        vpa[((size_t)e*NN+n)*FF + f] = aa;
    }
}

/* ------------ K2: routing + positional enc + param feats ------------ */
__global__ __launch_bounds__(256) void k_route(
    const float* __restrict__ x, const float* __restrict__ lines,
    const float* __restrict__ mg_w0, const float* __restrict__ mg_b0,
    const float* __restrict__ mg_w1, const float* __restrict__ mg_b1,
    float* __restrict__ pe_x, float* __restrict__ pfm,
    float* __restrict__ rawq, float* __restrict__ rw,
    int* __restrict__ counts, int* __restrict__ lists)
{
    __shared__ float slines[LINE*LINE];
    for (int i = threadIdx.x; i < LINE*LINE; i += 256) slines[i] = lines[i];
    __syncthreads();
    int b = blockIdx.x*256 + threadIdx.x;
    float4 xx = ((const float4*)x)[b];
    float c0 = xx.x, c1 = xx.y, c2 = xx.z, c3 = xx.w;

    float p = c3 * (float)(LINE-1);
    float pfl = floorf(p);
    float w = p - pfl;
    int il = (int)pfl;
    int ih = (int)fminf(fmaxf(pfl + 1.f, 0.f), (float)(LINE-1));
    for (int c = 0; c < FF; ++c) {
        float lo = slines[c*LINE+il], hi = slines[c*LINE+ih];
        pfm[(size_t)b*FF + c] = lo + w*(hi-lo);
    }
    float* pe = pe_x + (size_t)b*PED;
    pe[0]=c0; pe[1]=c1; pe[2]=c2;
    const float PI = 3.14159265358979323846f;
    float coords[3] = {c0,c1,c2};
#pragma unroll
    for (int cc = 0; cc < 3; ++cc) {
        float fr = PI;
        for (int k = 0; k < 10; ++k) {
            float s = coords[cc]*fr;
            pe[3 + cc*20 + k*2 + 0] = sinf(s);
            pe[3 + cc*20 + k*2 + 1] = cosf(s);
            fr *= 2.f;
        }
    }
    float acc[4] = {mg_b1[0], mg_b1[1], mg_b1[2], mg_b1[3]};
    for (int j = 0; j < 64; ++j) {
        float h = fmaf(c0, mg_w0[j], fmaf(c1, mg_w0[64+j], fmaf(c2, mg_w0[128+j], mg_b0[j])));
        h = fmaxf(h, 0.f);
#pragma unroll
        for (int e4 = 0; e4 < 4; ++e4) acc[e4] = fmaf(h, mg_w1[j*4+e4], acc[e4]);
    }
#pragma unroll
    for (int e4 = 0; e4 < 4; ++e4) rawq[(size_t)b*4 + e4] = acc[e4];
    float m = fmaxf(fmaxf(acc[0],acc[1]), fmaxf(acc[2],acc[3]));
    float ex[4], den = 0.f;
#pragma unroll
    for (int e4 = 0; e4 < 4; ++e4) { ex[e4] = expf(acc[e4]-m); den += ex[e4]; }
    float pr[4];
#pragma unroll
    for (int e4 = 0; e4 < 4; ++e4) pr[e4] = fmaxf(ex[e4]/den, 1e-8f);
    int i0 = 0;
#pragma unroll
    for (int e4 = 1; e4 < 4; ++e4) if (pr[e4] > pr[i0]) i0 = e4;
    int i1 = -1;
#pragma unroll
    for (int e4 = 0; e4 < 4; ++e4) {
        if (e4 == i0) continue;
        if (i1 < 0 || pr[e4] > pr[i1]) i1 = e4;
    }
    float vs = pr[i0] + pr[i1];
    rw[b*2+0] = pr[i0]/vs;
    rw[b*2+1] = pr[i1]/vs;
    int p0 = atomicAdd(&counts[i0], 1);
    lists[i0*BB + p0] = b*2 + 0;
    int p1 = atomicAdd(&counts[i1], 1);
    lists[i1*BB + p1] = b*2 + 1;
}

/* ------------ K3a: SIREN MLP + LN + q  (LDS-light VGPR-light, 3 blk/CU) ------------ */
__global__ __launch_bounds__(512, 6) void k_mlp(
    const float* __restrict__ pe_x,
    const float* __restrict__ enc_w0, const float* __restrict__ enc_b0,
    const float* __restrict__ enc_wh, const float* __restrict__ enc_bh,
    const float* __restrict__ enc_wo, const float* __restrict__ enc_bo,
    const float* __restrict__ ln_g, const float* __restrict__ ln_b,
    const float* __restrict__ wq,
    const int* __restrict__ counts, const int* __restrict__ lists,
    float* __restrict__ qv, float* __restrict__ smlpw)
{
    const int e = blockIdx.y;
    const int base = blockIdx.x * TS;
    const int cnt = counts[e];
    if (base >= cnt) return;

    __shared__ float sh[TS*HH];       /* 32KB */
    __shared__ float swt[4096];       /* 16KB weight tiles */
    __shared__ int   slist[TS];

    const int tid = threadIdx.x;
    const int lane = tid & 63;
    const int wv = tid >> 6;
    const int r0 = wv*4;

    if (tid < TS) {
        int idx = base + tid;
        if (idx >= cnt) idx = cnt - 1;
        slist[tid] = lists[e*BB + idx];
    }
    __syncthreads();
    for (int i = tid; i < TS*64; i += 512) {
        int s = i >> 6, j = i & 63;
        int bq = slist[s] >> 1;
        sh[s*HH + j] = (j < PED) ? pe_x[(size_t)bq*PED + j] : 0.f;
    }
    /* first tile-stage barrier covers pe writes */

    float acc[4][4];

    /* L0: 63 -> 256, 16-row tiles */
    {
        const float* W = enc_w0 + (size_t)e*PED*HH;
#pragma unroll
        for (int s = 0; s < 4; ++s)
#pragma unroll
            for (int j = 0; j < 4; ++j) acc[s][j] = 0.f;
#pragma unroll 1
        for (int t = 0; t < 4; ++t) {
            int rbase = t*16;
            int rows = (PED - rbase < 16) ? (PED - rbase) : 16;
            int total = rows*HH;
            __syncthreads();
            for (int i = tid*4; i < total; i += 2048)
                *(float4*)&swt[i] = *(const float4*)&W[rbase*HH + i];
            __syncthreads();
#pragma unroll 1
            for (int k = 0; k < rows; ++k) {
                float4 w4 = *(const float4*)&swt[k*HH + 4*lane];
#pragma unroll
                for (int s = 0; s < 4; ++s) {
                    float hv = sh[(r0+s)*HH + rbase + k];
                    acc[s][0] = fmaf(hv, w4.x, acc[s][0]);
                    acc[s][1] = fmaf(hv, w4.y, acc[s][1]);
                    acc[s][2] = fmaf(hv, w4.z, acc[s][2]);
                    acc[s][3] = fmaf(hv, w4.w, acc[s][3]);
                }
            }
        }
        __syncthreads();   /* all waves done reading pe before overwrite */
        float4 b4 = *(const float4*)&enc_b0[e*HH + 4*lane];
#pragma unroll
        for (int s = 0; s < 4; ++s) {
            float4 o;
            o.x = sinf(30.0f*(acc[s][0] + b4.x));
            o.y = sinf(30.0f*(acc[s][1] + b4.y));
            o.z = sinf(30.0f*(acc[s][2] + b4.z));
            o.w = sinf(30.0f*(acc[s][3] + b4.w));
            *(float4*)&sh[(r0+s)*HH + 4*lane] = o;
        }
    }

    /* L1, L2: 256 -> 256, 16-row tiles */
#pragma unroll 1
    for (int layer = 0; layer < 2; ++layer) {
        const float* W = enc_wh + ((size_t)(e*2+layer))*HH*HH;
#pragma unroll
        for (int s = 0; s < 4; ++s)
#pragma unroll
            for (int j = 0; j < 4; ++j) acc[s][j] = 0.f;
#pragma unroll 1
        for (int t = 0; t < 16; ++t) {
            __syncthreads();
            for (int i = tid*4; i < 4096; i += 2048)
                *(float4*)&swt[i] = *(const float4*)&W[t*16*HH + i];
            __syncthreads();
#pragma unroll 1
            for (int k4 = 0; k4 < 4; ++k4) {
                float4 h4[4];
#pragma unroll
                for (int s = 0; s < 4; ++s)
                    h4[s] = *(const float4*)&sh[(r0+s)*HH + t*16 + 4*k4];
#pragma unroll
                for (int kk = 0; kk < 4; ++kk) {
                    float4 w4 = *(const float4*)&swt[(4*k4+kk)*HH + 4*lane];
#pragma unroll
                    for (int s = 0; s < 4; ++s) {
                        float hv = (kk==0)?h4[s].x:((kk==1)?h4[s].y:((kk==2)?h4[s].z:h4[s].w));
                        acc[s][0] = fmaf(hv, w4.x, acc[s][0]);
                        acc[s][1] = fmaf(hv, w4.y, acc[s][1]);
                        acc[s][2] = fmaf(hv, w4.z, acc[s][2]);
                        acc[s][3] = fmaf(hv, w4.w, acc[s][3]);
                    }
                }
            }
        }
        __syncthreads();
        float4 b4 = *(const float4*)&enc_bh[(e*2+layer)*HH + 4*lane];
#pragma unroll
        for (int s = 0; s < 4; ++s) {
            float4 o;
            o.x = sinf(30.0f*(acc[s][0] + b4.x));
            o.y = sinf(30.0f*(acc[s][1] + b4.y));
            o.z = sinf(30.0f*(acc[s][2] + b4.z));
            o.w = sinf(30.0f*(acc[s][3] + b4.w));
            *(float4*)&sh[(r0+s)*HH + 4*lane] = o;
        }
    }

    /* out layer: 256 -> 64, 64-row tiles; smlp in regs */
    float smlp_r[4];
    {
        const float* W = enc_wo + (size_t)e*HH*FF;
        float a2o[4] = {0.f,0.f,0.f,0.f};
#pragma unroll 1
        for (int t = 0; t < 4; ++t) {
            __syncthreads();
            for (int i = tid*4; i < 4096; i += 2048)
                *(float4*)&swt[i] = *(const float4*)&W[t*64*FF + i];
            __syncthreads();
#pragma unroll 1
            for (int k4 = 0; k4 < 16; ++k4) {
                float4 h4[4];
#pragma unroll
                for (int s = 0; s < 4; ++s)
                    h4[s] = *(const float4*)&sh[(r0+s)*HH + t*64 + 4*k4];
#pragma unroll
                for (int kk = 0; kk < 4; ++kk) {
                    float w = swt[(4*k4+kk)*FF + lane];
#pragma unroll
                    for (int s = 0; s < 4; ++s) {
                        float hv = (kk==0)?h4[s].x:((kk==1)?h4[s].y:((kk==2)?h4[s].z:h4[s].w));
                        a2o[s] = fmaf(hv, w, a2o[s]);
                    }
                }
            }
        }
        float bv = enc_bo[e*FF + lane];
#pragma unroll
        for (int s = 0; s < 4; ++s) smlp_r[s] = a2o[s] + bv;
    }

    /* stage wq; LN + q; write qv/smlp by entry */
    {
        const float* Wq = wq + (size_t)e*FF*FF;
        __syncthreads();
        for (int i = tid*4; i < 4096; i += 2048)
            *(float4*)&swt[i] = *(const float4*)&Wq[i];
        __syncthreads();
        float g = ln_g[lane], bb2 = ln_b[lane];
#pragma unroll 1
        for (int s = 0; s < 4; ++s) {
            float hv = smlp_r[s];
            float sm = hv, s2 = hv*hv;
            wred_sum2(sm, s2);
            float mean = sm * (1.f/64.f);
            float var = s2 * (1.f/64.f) - mean*mean;
            float lnv = (hv - mean) * rsqrtf(var + 1e-5f) * g + bb2;
            sh[(r0+s)*HH + lane] = lnv;
            float qa = 0.f;
#pragma unroll 1
            for (int c4 = 0; c4 < 16; ++c4) {
                float4 l4 = *(const float4*)&sh[(r0+s)*HH + 4*c4];
                qa = fmaf(l4.x, swt[(4*c4+0)*FF + lane], qa);
                qa = fmaf(l4.y, swt[(4*c4+1)*FF + lane], qa);
                qa = fmaf(l4.z, swt[(4*c4+2)*FF + lane], qa);
                qa = fmaf(l4.w, swt[(4*c4+3)*FF + lane], qa);
            }
            if (base + r0 + s < cnt) {
                size_t entry = (size_t)slist[r0+s];
                qv[entry*FF + lane] = qa;
                smlpw[entry*FF + lane] = smlp_r[s];
            }
        }
    }
}

/* ------------ K3b: scores + top-16 + adapter (VGPR-heavy, no spill) ------------ */
__global__ __launch_bounds__(512, 4) void k_attn(
    const float* __restrict__ pfm,
    const float* __restrict__ kp, const float* __restrict__ vp,
    const float* __restrict__ vpa,
    const float* __restrict__ qv, const float* __restrict__ smlpw,
    const float* __restrict__ aw0, const float* __restrict__ ab0,
    const float* __restrict__ aw1, const float* __restrict__ ab1,
    const float* __restrict__ adg, const float* __restrict__ adb,
    const int* __restrict__ counts, const int* __restrict__ lists,
    float* __restrict__ eo)
{
    const int e = blockIdx.y;
    const int base = blockIdx.x * TS;
    const int cnt = counts[e];
    if (base >= cnt) return;

    __shared__ float swt[8192];       /* 32KB: kp chunk [64][68]; then a0b|w1 */
    __shared__ float sq[TS*FF];       /* 8KB */
    __shared__ float pl[8*1024];      /* 32KB wave-private transpose buffers */
    __shared__ float wr_l[8*TOPK];
    __shared__ int   slist[TS];

    const int tid = threadIdx.x;
    const int lane = tid & 63;
    const int wv = tid >> 6;
    const int r0 = wv*4;

    if (tid < TS) {
        int idx = base + tid;
        if (idx >= cnt) idx = cnt - 1;
        slist[tid] = lists[e*BB + idx];
    }
    __syncthreads();
    for (int i = tid; i < TS*64; i += 512) {
        int s = i >> 6, c = i & 63;
        sq[i] = qv[(size_t)slist[s]*FF + c];
    }
    /* first chunk-stage barrier covers sq writes */

    /* score chunks */
    float sc[4][16];
    {
        const float* kpe = kp + (size_t)e*NN*FF;
        const int str = tid >> 3;
        const int stc = (tid & 7) * 8;
#pragma unroll 1
        for (int c = 0; c < 16; ++c) {
            __syncthreads();
            {
                const float* src = kpe + (size_t)(c*64 + str)*FF + stc;
                float* dst = &swt[str*68 + stc];
                *(float4*)(dst+0) = *(const float4*)(src+0);
                *(float4*)(dst+4) = *(const float4*)(src+4);
            }
            __syncthreads();
            float a0 = 0.f, a1 = 0.f, a2s = 0.f, a3 = 0.f;
#pragma unroll
            for (int f4 = 0; f4 < 16; ++f4) {
                float4 k4 = *(const float4*)&swt[lane*68 + 4*f4];
                float4 q0 = *(const float4*)&sq[(r0+0)*FF + 4*f4];
                float4 q1 = *(const float4*)&sq[(r0+1)*FF + 4*f4];
                float4 q2 = *(const float4*)&sq[(r0+2)*FF + 4*f4];
                float4 q3 = *(const float4*)&sq[(r0+3)*FF + 4*f4];
                a0 = fmaf(k4.x,q0.x,fmaf(k4.y,q0.y,fmaf(k4.z,q0.z,fmaf(k4.w,q0.w,a0))));
                a1 = fmaf(k4.x,q1.x,fmaf(k4.y,q1.y,fmaf(k4.z,q1.z,fmaf(k4.w,q1.w,a1))));
                a2s= fmaf(k4.x,q2.x,fmaf(k4.y,q2.y,fmaf(k4.z,q2.z,fmaf(k4.w,q2.w,a2s))));
                a3 = fmaf(k4.x,q3.x,fmaf(k4.y,q3.y,fmaf(k4.z,q3.z,fmaf(k4.w,q3.w,a3))));
            }
            sc[0][c]=a0; sc[1][c]=a1; sc[2][c]=a2s; sc[3][c]=a3;
        }
    }

    /* restage swt: a0b | w1 */
    __syncthreads();
    {
        const float* a0bG = aw0 + ((size_t)e*128 + 64)*FF;
        const float* w1G  = aw1 + (size_t)e*FF*FF;
        for (int i = tid*4; i < 4096; i += 2048) {
            *(float4*)&swt[i]        = *(const float4*)&a0bG[i];
            *(float4*)&swt[4096 + i] = *(const float4*)&w1G[i];
        }
    }
    __syncthreads();

    const float* vpe  = vp  + (size_t)e*NN*FF;
    const float* vpae = vpa + (size_t)e*NN*FF;
    const float agv = adg[e*FF + lane], abv = adb[e*FF + lane];
    const float ab0v = ab0[e*FF + lane];
    const float ab1v = ab1[e*FF + lane];
    float* plw = &pl[wv*1024];

#pragma unroll      /* full unroll: all sc/rns/a2 indices static -> no scratch */
    for (int u = 0; u < 4; ++u) {
        int s = r0 + u;
        int entry = slist[s];
        int bq = entry >> 1;

        /* pf half of adapter layer 1 (weights in LDS) */
        float pp = ab0v;
        {
            const float* pfr = pfm + (size_t)bq*FF;
#pragma unroll 1
            for (int c4 = 0; c4 < 16; ++c4) {
                float4 p4 = *(const float4*)&pfr[4*c4];
                pp = fmaf(p4.x, swt[(4*c4+0)*FF + lane], pp);
                pp = fmaf(p4.y, swt[(4*c4+1)*FF + lane], pp);
                pp = fmaf(p4.z, swt[(4*c4+2)*FF + lane], pp);
                pp = fmaf(p4.w, swt[(4*c4+3)*FF + lane], pp);
            }
        }

        /* 16 argmax rounds — NO gathers inside (decoupled) */
        int rns[16];
        unsigned taken = 0u;
        bool need = true;
        float bv = -1e30f; int bn = 0x7fffffff;
        float v0max = 0.f, wsum = 0.f;
#pragma unroll
        for (int r = 0; r < TOPK; ++r) {
            if (need) {
                bv = -1e30f; bn = 0x7fffffff;
#pragma unroll
                for (int c = 0; c < 16; ++c) {
                    float v = sc[u][c];
                    int n = c*64 + lane;
                    bool ok = !((taken >> c) & 1u);
                    bool better = ok && (v > bv || (v == bv && n < bn));
                    bv = better ? v : bv;
                    bn = better ? n : bn;
                }
                need = false;
            }
            float rv = bv; int rn = bn;
#pragma unroll
            for (int off = 32; off > 0; off >>= 1) {
                float ov = __shfl_xor(rv, off, 64);
                int on = __shfl_xor(rn, off, 64);
                bool better = (ov > rv) || (ov == rv && on < rn);
                rv = better ? ov : rv;
                rn = better ? on : rn;
            }
            if (r == 0) v0max = rv;
            float wr = expf((rv - v0max) * 0.125f);
            wsum += wr;
            if (lane == 0) wr_l[wv*TOPK + r] = wr;
            if ((rn & 63) == lane) { taken |= 1u << (rn >> 6); need = true; }
            rns[r] = rn;
        }

        /* batched vpa gathers (rn wave-uniform -> coalesced 256B rows, 16 in flight) */
        float pav[16];
#pragma unroll
        for (int r = 0; r < TOPK; ++r)
            pav[r] = vpae[(size_t)rns[r]*FF + lane];
        /* pack relu'd p -> LDS, XOR slot swizzle */
#pragma unroll
        for (int q = 0; q < 4; ++q) {
            int slot = q ^ (lane & 3);
            float4 o;
            o.x = fmaxf(pav[4*q+0] + pp, 0.f);
            o.y = fmaxf(pav[4*q+1] + pp, 0.f);
            o.z = fmaxf(pav[4*q+2] + pp, 0.f);
            o.w = fmaxf(pav[4*q+3] + pp, 0.f);
            *(float4*)&plw[lane*16 + slot*4] = o;
        }
        /* adapter layer 2 in regs (w1 in LDS at swt+4096) */
        float a2[16];
#pragma unroll
        for (int r = 0; r < 16; ++r) a2[r] = ab1v;
#pragma unroll 1
        for (int j4 = 0; j4 < 16; ++j4) {
            const float* plj = &plw[j4*64];
#pragma unroll
            for (int jj = 0; jj < 4; ++jj) {
                float w = swt[4096 + (4*j4+jj)*FF + lane];
#pragma unroll
                for (int lq = 0; lq < 4; ++lq) {
                    float4 d = *(const float4*)&plj[jj*16 + ((lq ^ jj) * 4)];
                    a2[4*lq+0] = fmaf(d.x, w, a2[4*lq+0]);
                    a2[4*lq+1] = fmaf(d.y, w, a2[4*lq+1]);
                    a2[4*lq+2] = fmaf(d.z, w, a2[4*lq+2]);
                    a2[4*lq+3] = fmaf(d.w, w, a2[4*lq+3]);
                }
            }
        }
        /* batched vp gathers for the residual term */
        float vvt[16];
#pragma unroll
        for (int r = 0; r < TOPK; ++r)
            vvt[r] = vpe[(size_t)rns[r]*FF + lane];
        /* LN + residual + attn-weighted sum */
        float outacc = 0.f;
#pragma unroll
        for (int r = 0; r < TOPK; ++r) {
            float av = a2[r];
            float sm = av, s2 = av*av;
            wred_sum2(sm, s2);
            float mean = sm * (1.f/64.f);
            float var = s2 * (1.f/64.f) - mean*mean;
            float lnv = (av - mean) * rsqrtf(var + 1e-5f) * agv + abv;
            outacc = fmaf(wr_l[wv*TOPK + r], vvt[r] + lnv, outacc);
        }
        float res = outacc / wsum + smlpw[(size_t)entry*FF + lane];
        if (base + s < cnt) eo[(size_t)entry*FF + lane] = res;
    }
}

/* ------------ K4: combine + final MLP, LDS-staged weights ------------ */
__global__ __launch_bounds__(512, 6) void k_final(
    const float* __restrict__ eo, const float* __restrict__ rw,
    const float* __restrict__ fw0, const float* __restrict__ fb0,
    const float* __restrict__ fw1, const float* __restrict__ fb1,
    const float* __restrict__ fw2, const float* __restrict__ fb2,
    const float* __restrict__ fw3, const float* __restrict__ fb3,
    float* __restrict__ refined)
{
    __shared__ float sh[TS*HH];       /* 32KB */
    __shared__ float swt[4096];       /* 16KB */
    const int tid = threadIdx.x, lane = tid & 63, wv = tid >> 6;
    const int sbase = blockIdx.x * TS;
    const int r0 = wv*4;
    for (int i = tid; i < TS*64; i += 512) {
        int s = i >> 6, c = i & 63;
        int b = sbase + s;
        sh[s*HH + c] = rw[b*2]*eo[(size_t)(b*2)*FF + c]
                     + rw[b*2+1]*eo[(size_t)(b*2+1)*FF + c];
    }
    float acc[4][4];
    /* L0: 64 -> 256 relu, 16-row tiles */
    {
#pragma unroll
        for (int s = 0; s < 4; ++s)
#pragma unroll
            for (int j = 0; j < 4; ++j) acc[s][j] = 0.f;
#pragma unroll 1
        for (int t = 0; t < 4; ++t) {
            __syncthreads();
            for (int i = tid*4; i < 4096; i += 2048)
                *(float4*)&swt[i] = *(const float4*)&fw0[t*16*HH + i];
            __syncthreads();
#pragma unroll 1
            for (int k = 0; k < 16; ++k) {
                float4 w4 = *(const float4*)&swt[k*HH + 4*lane];
#pragma unroll
                for (int s = 0; s < 4; ++s) {
                    float hv = sh[(r0+s)*HH + t*16 + k];
                    acc[s][0] = fmaf(hv, w4.x, acc[s][0]);
                    acc[s][1] = fmaf(hv, w4.y, acc[s][1]);
                    acc[s][2] = fmaf(hv, w4.z, acc[s][2]);
                    acc[s][3] = fmaf(hv, w4.w, acc[s][3]);
                }
            }
        }
        __syncthreads();
        float4 b4 = *(const float4*)&fb0[4*lane];
#pragma unroll
        for (int s = 0; s < 4; ++s) {
            float4 o;
            o.x = fmaxf(acc[s][0] + b4.x, 0.f);
            o.y = fmaxf(acc[s][1] + b4.y, 0.f);
            o.z = fmaxf(acc[s][2] + b4.z, 0.f);
            o.w = fmaxf(acc[s][3] + b4.w, 0.f);
            *(float4*)&sh[(r0+s)*HH + 4*lane] = o;
        }
    }
    /* L1, L2: 256 -> 256 relu, 16-row tiles */
#pragma unroll 1
    for (int layer = 0; layer < 2; ++layer) {
        const float* W  = layer ? fw2 : fw1;
        const float* bi = layer ? fb2 : fb1;
#pragma unroll
        for (int s = 0; s < 4; ++s)
#pragma unroll
            for (int j = 0; j < 4; ++j) acc[s][j] = 0.f;
#pragma unroll 1
        for (int t = 0; t < 16; ++t) {
            __syncthreads();
            for (int i = tid*4; i < 4096; i += 2048)
                *(float4*)&swt[i] = *(const float4*)&W[t*16*HH + i];
            __syncthreads();
#pragma unroll 1
            for (int k4 = 0; k4 < 4; ++k4) {
                float4 h4[4];
#pragma unroll
                for (int s = 0; s < 4; ++s)
                    h4[s] = *(const float4*)&sh[(r0+s)*HH + t*16 + 4*k4];
#pragma unroll
                for (int kk = 0; kk < 4; ++kk) {
                    float4 w4 = *(const float4*)&swt[(4*k4+kk)*HH + 4*lane];
#pragma unroll
                    for (int s = 0; s < 4; ++s) {
                        float hv = (kk==0)?h4[s].x:((kk==1)?h4[s].y:((kk==2)?h4[s].z:h4[s].w));
                        acc[s][0] = fmaf(hv, w4.x, acc[s][0]);
                        acc[s][1] = fmaf(hv, w4.y, acc[s][1]);
                        acc[s][2] = fmaf(hv, w4.z, acc[s][2]);
                        acc[s][3] = fmaf(hv, w4.w, acc[s][3]);
                    }
                }
            }
        }
        __syncthreads();
        float4 b4 = *(const float4*)&bi[4*lane];
#pragma unroll
        for (int s = 0; s < 4; ++s) {
            float4 o;
            o.x = fmaxf(acc[s][0] + b4.x, 0.f);
            o.y = fmaxf(acc[s][1] + b4.y, 0.f);
            o.z = fmaxf(acc[s][2] + b4.z, 0.f);
            o.w = fmaxf(acc[s][3] + b4.w, 0.f);
            *(float4*)&sh[(r0+s)*HH + 4*lane] = o;
        }
    }
    /* L3: 256 -> 1, sigmoid */
    {
        float4 w4 = *(const float4*)&fw3[4*lane];
#pragma unroll 1
        for (int s = 0; s < 4; ++s) {
            float4 h4 = *(const float4*)&sh[(r0+s)*HH + 4*lane];
            float part = h4.x*w4.x + h4.y*w4.y + h4.z*w4.z + h4.w*w4.w;
            float tot = wred_sum(part) + fb3[0];
            float r = 1.f/(1.f + expf(-tot));
            if (lane == 0) refined[sbase + r0 + s] = r;
        }
    }
}

extern "C" void kernel_launch(void* const* d_in, const int* in_sizes, int n_in,
                              void* d_out, int out_size, void* d_ws, size_t ws_size,
                              hipStream_t stream)
{
    const float* x      = (const float*)d_in[0];
    const float* lines  = (const float*)d_in[1];
    const float* mem_k  = (const float*)d_in[2];
    const float* mem_v  = (const float*)d_in[3];
    const float* enc_w0 = (const float*)d_in[4];
    const float* enc_b0 = (const float*)d_in[5];
    const float* enc_wh = (const float*)d_in[6];
    const float* enc_bh = (const float*)d_in[7];
    const float* enc_wo = (const float*)d_in[8];
    const float* enc_bo = (const float*)d_in[9];
    const float* ln_g   = (const float*)d_in[10];
    const float* ln_b   = (const float*)d_in[11];
    const float* wq     = (const float*)d_in[12];
    const float* wk     = (const float*)d_in[13];
    const float* wv_    = (const float*)d_in[14];
    const float* ad_w0  = (const float*)d_in[15];
    const float* ad_b0  = (const float*)d_in[16];
    const float* ad_w1  = (const float*)d_in[17];
    const float* ad_b1  = (const float*)d_in[18];
    const float* ad_g   = (const float*)d_in[19];
    const float* ad_b   = (const float*)d_in[20];
    const float* mg_w0  = (const float*)d_in[21];
    const float* mg_b0  = (const float*)d_in[22];
    const float* mg_w1  = (const float*)d_in[23];
    const float* mg_b1  = (const float*)d_in[24];
    const float* fw0    = (const float*)d_in[25];
    const float* fb0    = (const float*)d_in[26];
    const float* fw1    = (const float*)d_in[27];
    const float* fb1    = (const float*)d_in[28];
    const float* fw2    = (const float*)d_in[29];
    const float* fb2    = (const float*)d_in[30];
    const float* fw3    = (const float*)d_in[31];
    const float* fb3    = (const float*)d_in[32];

    float* out_ref = (float*)d_out;           /* refined: B */
    float* out_rq  = (float*)d_out + BB;      /* raw_q: B*4 */

    float* ws  = (float*)d_ws;
    float* kp  = ws + OFF_KP;
    float* vp  = ws + OFF_VP;
    float* vpa = ws + OFF_VPA;
    float* pe  = ws + OFF_PE;
    float* pfm = ws + OFF_PF;
    float* eo  = ws + OFF_EO;
    float* rw  = ws + OFF_RW;
    float* qvw = ws + OFF_QV;
    float* smw = ws + OFF_SM;
    float* wpw = ws + OFF_WP;
    int*  cnts = (int*)(ws + OFF_CNT);
    int*  lst  = (int*)(ws + OFF_LIST);

    hipMemsetAsync(cnts, 0, EE*sizeof(int), stream);
    k_prep<<<dim3(EE), dim3(256), 0, stream>>>(wv_, ad_w0, wpw);
    k_proj<<<dim3(EE*64), dim3(256), 0, stream>>>(mem_k, mem_v, wk, wv_, wpw, kp, vp, vpa);
    k_route<<<dim3(BB/256), dim3(256), 0, stream>>>(x, lines, mg_w0, mg_b0, mg_w1, mg_b1,
                                                    pe, pfm, out_rq, rw, cnts, lst);
    k_mlp<<<dim3(NBX, EE), dim3(512), 0, stream>>>(pe,
        enc_w0, enc_b0, enc_wh, enc_bh, enc_wo, enc_bo, ln_g, ln_b, wq,
        cnts, lst, qvw, smw);
    k_attn<<<dim3(NBX, EE), dim3(512), 0, stream>>>(pfm, kp, vp, vpa, qvw, smw,
        ad_w0, ad_b0, ad_w1, ad_b1, ad_g, ad_b, cnts, lst, eo);
    k_final<<<dim3(BB/TS), dim3(512), 0, stream>>>(eo, rw, fw0, fb0, fw1, fb1,
                                                   fw2, fb2, fw3, fb3, out_ref);
}